// Round 1
// baseline (154.035 us; speedup 1.0000x reference)
//
#include <hip/hip_runtime.h>
#include <math.h>

#define B_ 1000
#define D_ 8
#define PRE_ 98
#define NXT_ 2048
#define J_ 32
#define K_ 64
#define A_ 5

#define BM 64
#define BN 64
#define OCN 4
#define OSPAN (NXT_ / OCN)   // 512
#define NOT_ (OSPAN / BN)    // 8 o-tiles per block

#define XS_STRIDE (BM + 4)   // 68 floats: 272B rows, 16B-aligned, banks spread
#define SUB_STRIDE (BN + 1)  // 65
#define XS_FLOATS (PRE_ * XS_STRIDE)   // 6664
#define SUB_FLOATS (BM * SUB_STRIDE)   // 4160

// ws layout (floats):
//   [0, 1024000)        S1part[oc][b][d][j]
//   [1024000, 1024512)  spsum[512]   (block partial sums,  bid=(d*4+oc)*16+bt)
//   [1024512, 1025024)  spsq[512]
//   [1025024, 1025280)  wcsum[256]
//   [1025280, 1025536)  coef[256]
//   [1025536, 1025568)  konst[32]

__global__ __launch_bounds__(256) void kpre_wcsum(const float* __restrict__ Wc,
                                                  float* __restrict__ wcsum) {
  __shared__ float red[256];
  const int dj = blockIdx.x;
  const float* p = Wc + (size_t)dj * NXT_;
  float s = 0.0f;
  for (int i = threadIdx.x; i < NXT_; i += 256) s += p[i];
  red[threadIdx.x] = s;
  __syncthreads();
  for (int st = 128; st > 0; st >>= 1) {
    if (threadIdx.x < st) red[threadIdx.x] += red[threadIdx.x + st];
    __syncthreads();
  }
  if (threadIdx.x == 0) wcsum[dj] = red[0];
}

__global__ __launch_bounds__(256) void k1_gemm(
    const float* __restrict__ x, const float* __restrict__ W1,
    const float* __restrict__ b1, const float* __restrict__ Wc,
    float* __restrict__ S1part, float* __restrict__ spsum,
    float* __restrict__ spsq) {
  __shared__ float smem[XS_FLOATS * 2];   // 53.3 KB total
  float* xs_t  = smem;                    // [98][68] transposed x tile
  float* w_t   = smem + XS_FLOATS;        // [98][68] transposed W1 tile
  float* sub_l = w_t;                     // [64][65] reuses w_t region
  float* wc_l  = w_t + SUB_FLOATS;        // [32][65]

  const int bt = blockIdx.x, oc = blockIdx.y, d = blockIdx.z;
  const int tid = threadIdx.x;
  const int tx = tid & 15, ty = tid >> 4;
  const int row0 = bt * BM;

  // load x tile transposed (zero-pad rows >= B_)
  for (int idx = tid; idx < BM * PRE_; idx += 256) {
    int r = idx / PRE_;
    int i = idx - r * PRE_;
    int gb = row0 + r;
    float v = (gb < B_) ? x[(size_t)gb * (D_ * PRE_) + d * PRE_ + i] : 0.0f;
    xs_t[i * XS_STRIDE + r] = v;
  }

  float acc8[8];
#pragma unroll
  for (int jj = 0; jj < 8; ++jj) acc8[jj] = 0.0f;
  float lsum = 0.0f, lsq = 0.0f;

  const int drow = tid >> 2;        // 0..63
  const int j0 = (tid & 3) * 8;     // 0,8,16,24

  for (int ot = 0; ot < NOT_; ++ot) {
    const int o0 = oc * OSPAN + ot * BN;
    // load W1 tile transposed
    for (int idx = tid; idx < BN * PRE_; idx += 256) {
      int o = idx / PRE_;
      int i = idx - o * PRE_;
      w_t[i * XS_STRIDE + o] = W1[((size_t)d * NXT_ + o0 + o) * PRE_ + i];
    }
    __syncthreads();

    float acc[4][4];
#pragma unroll
    for (int r = 0; r < 4; ++r)
#pragma unroll
      for (int c = 0; c < 4; ++c) acc[r][c] = 0.0f;

    const float* xa = xs_t + ty * 4;
    const float* wb = w_t + tx * 4;
#pragma unroll 2
    for (int k = 0; k < PRE_; ++k) {
      float4 a4 = *(const float4*)(xa + k * XS_STRIDE);
      float4 b4 = *(const float4*)(wb + k * XS_STRIDE);
      float ar[4] = {a4.x, a4.y, a4.z, a4.w};
      float br[4] = {b4.x, b4.y, b4.z, b4.w};
#pragma unroll
      for (int r = 0; r < 4; ++r)
#pragma unroll
        for (int c = 0; c < 4; ++c) acc[r][c] = fmaf(ar[r], br[c], acc[r][c]);
    }
    __syncthreads();  // all threads done reading w_t -> safe to overwrite

    // bias + relu + stats, store sub tile into (former w_t) region
    {
      float bv[4];
#pragma unroll
      for (int c = 0; c < 4; ++c) bv[c] = b1[d * NXT_ + o0 + tx * 4 + c];
#pragma unroll
      for (int r = 0; r < 4; ++r) {
        int grow = row0 + ty * 4 + r;
        bool val = grow < B_;
#pragma unroll
        for (int c = 0; c < 4; ++c) {
          float s = fmaxf(acc[r][c] + bv[c], 0.0f);
          if (val) { lsum += s; lsq = fmaf(s, s, lsq); }
          sub_l[(ty * 4 + r) * SUB_STRIDE + tx * 4 + c] = s;
        }
      }
    }
    // load Wc tile [32][64]
    for (int idx = tid; idx < J_ * BN; idx += 256) {
      int j = idx >> 6;
      int c = idx & 63;
      wc_l[j * SUB_STRIDE + c] = Wc[((size_t)d * J_ + j) * NXT_ + o0 + c];
    }
    __syncthreads();

    // mini-GEMM: acc8[j] += sub[row][k] * Wc[j][k]
    const float* subr = sub_l + drow * SUB_STRIDE;
#pragma unroll 4
    for (int k = 0; k < BN; ++k) {
      float a = subr[k];
#pragma unroll
      for (int jj = 0; jj < 8; ++jj)
        acc8[jj] = fmaf(a, wc_l[(j0 + jj) * SUB_STRIDE + k], acc8[jj]);
    }
    __syncthreads();
  }

  // write S1 partial (one exclusive slot per (oc,b,d,j): deterministic, no atomics)
  {
    int grow = row0 + drow;
    if (grow < B_) {
      float* p = S1part + ((size_t)(oc * B_ + grow) * D_ + d) * J_ + j0;
#pragma unroll
      for (int jj = 0; jj < 8; ++jj) p[jj] = acc8[jj];
    }
  }

  // stats block-reduce (reuse xs_t region; last read was before final sync)
  {
    float* red = smem;
    red[tid] = lsum;
    red[256 + tid] = lsq;
    __syncthreads();
    for (int st = 128; st > 0; st >>= 1) {
      if (tid < st) {
        red[tid] += red[tid + st];
        red[256 + tid] += red[256 + tid + st];
      }
      __syncthreads();
    }
    if (tid == 0) {
      int bid = (d * 4 + oc) * 16 + bt;
      spsum[bid] = red[0];
      spsq[bid] = red[256];
    }
  }
}

__global__ __launch_bounds__(256) void k2_prep(
    const float* __restrict__ spsum, const float* __restrict__ spsq,
    const float* __restrict__ wcsum, const float* __restrict__ bc,
    const float* __restrict__ b_mat, const float* __restrict__ h_mat,
    const float* __restrict__ a_mat, const float* __restrict__ noise,
    const float* __restrict__ indicator, float* __restrict__ coef,
    float* __restrict__ konst) {
  const int tid = threadIdx.x;
  __shared__ float mvals[8], vvals[8];
  __shared__ float sh_gm, sh_inv;
  __shared__ float offs[D_][J_];

  if (tid < 8) {
    float s = 0.0f, q = 0.0f;
    for (int i = 0; i < 64; ++i) {
      s += spsum[tid * 64 + i];
      q += spsq[tid * 64 + i];
    }
    const float inv_cnt = 1.0f / ((float)B_ * (float)NXT_);
    float m = s * inv_cnt;
    mvals[tid] = m;
    vvals[tid] = q * inv_cnt - m * m;
  }
  __syncthreads();
  if (tid == 0) {
    float gm = 0.0f, gv = 0.0f;
    for (int dd = 0; dd < 8; ++dd) { gm += mvals[dd]; gv += vvals[dd]; }
    gm *= 0.125f;
    gv *= 0.125f;
    sh_gm = gm;
    sh_inv = 1.0f / sqrtf(gv + 1e-6f);
  }
  __syncthreads();
  {
    int dd = tid >> 5, j = tid & 31;
    float hs[A_] = {0, 0, 0, 0, 0};
    for (int k = 0; k < K_; ++k) {
      float indv = indicator[j * K_ + k];
      if (indv != 0.0f) {
        const float* hp = h_mat + ((size_t)dd * K_ + k) * A_;
#pragma unroll
        for (int a = 0; a < A_; ++a) hs[a] = fmaf(indv, hp[a], hs[a]);
      }
    }
    float hv = 0.0f;
#pragma unroll
    for (int a = 0; a < A_; ++a) hv = fmaf(hs[a], a_mat[j * A_ + a], hv);
    float c = b_mat[dd * J_ + j] * hv;
    coef[dd * J_ + j] = c * sh_inv;
    offs[dd][j] = c * (bc[dd * J_ + j] - sh_gm * wcsum[dd * J_ + j] * sh_inv);
  }
  __syncthreads();
  if (tid < J_) {
    float nz = 0.0f;
#pragma unroll
    for (int a = 0; a < A_; ++a)
      nz = fmaf(a_mat[tid * A_ + a], noise[tid * A_ + a], nz);
    float s = nz;
#pragma unroll
    for (int dd = 0; dd < D_; ++dd) s += offs[dd][tid];
    konst[tid] = s;
  }
}

#define W3S 33
#define W4S 99

__global__ __launch_bounds__(256) void k3_tail(
    const float* __restrict__ S1part, const float* __restrict__ coef,
    const float* __restrict__ konst, const float* __restrict__ cutb,
    const float* __restrict__ W3, const float* __restrict__ b3,
    const float* __restrict__ W4, const float* __restrict__ b4,
    const float* __restrict__ Wo, const float* __restrict__ bo,
    float* __restrict__ out) {
  __shared__ float W3l[98 * W3S];
  __shared__ float W4l[49 * W4S];
  __shared__ float Wol[10 * 49];
  __shared__ float b3l[98], b4l[49], bol[10];
  __shared__ float cutl[32], coefl[256], konstl[32];
  __shared__ float h1[8][32];
  __shared__ float h2[8][100];
  __shared__ float h3[8][52];
  __shared__ float lg[8][10];
  __shared__ float lsel[8];

  const int tid = threadIdx.x;
  for (int idx = tid; idx < 98 * 32; idx += 256) {
    int o = idx >> 5, j = idx & 31;
    W3l[o * W3S + j] = W3[idx];
  }
  for (int idx = tid; idx < 49 * 98; idx += 256) {
    int o = idx / 98, k = idx - o * 98;
    W4l[o * W4S + k] = W4[idx];
  }
  for (int idx = tid; idx < 490; idx += 256) Wol[idx] = Wo[idx];
  if (tid < 98) b3l[tid] = b3[tid];
  if (tid < 49) b4l[tid] = b4[tid];
  if (tid < 10) bol[tid] = bo[tid];
  if (tid < 32) {
    cutl[tid] = cutb[tid];
    konstl[tid] = konst[tid];
  }
  coefl[tid] = coef[tid];
  __syncthreads();

  const int row = tid >> 5, lane = tid & 31;
  const int b = blockIdx.x * 8 + row;   // 125*8 = 1000 exactly

  float rsum = konstl[lane];
#pragma unroll
  for (int dd = 0; dd < D_; ++dd) {
    float s = 0.0f;
#pragma unroll
    for (int ocx = 0; ocx < OCN; ++ocx)
      s += S1part[((size_t)(ocx * B_ + b) * D_ + dd) * J_ + lane];
    rsum = fmaf(coefl[dd * J_ + lane], s, rsum);
  }
  h1[row][lane] = fmaxf(rsum + cutl[lane], 0.0f);
  __syncthreads();

  for (int o = lane; o < 98; o += 32) {
    float a = b3l[o];
#pragma unroll
    for (int j = 0; j < 32; ++j) a = fmaf(h1[row][j], W3l[o * W3S + j], a);
    h2[row][o] = fmaxf(a, 0.0f);
  }
  __syncthreads();

  for (int o = lane; o < 49; o += 32) {
    float a = b4l[o];
    for (int k = 0; k < 98; ++k) a = fmaf(h2[row][k], W4l[o * W4S + k], a);
    h3[row][o] = fmaxf(a, 0.0f);
  }
  __syncthreads();

  if (lane < 10) {
    float a = bol[lane];
#pragma unroll
    for (int k = 0; k < 49; ++k) a = fmaf(h3[row][k], Wol[lane * 49 + k], a);
    lg[row][lane] = a;
  }
  __syncthreads();
  if (lane == 0) {
    float mx = lg[row][0];
    for (int i = 1; i < 10; ++i) mx = fmaxf(mx, lg[row][i]);
    float se = 0.0f;
    for (int i = 0; i < 10; ++i) se += expf(lg[row][i] - mx);
    lsel[row] = mx + logf(se);
  }
  __syncthreads();
  if (lane < 10) out[(size_t)b * 10 + lane] = lg[row][lane] - lsel[row];
}

extern "C" void kernel_launch(void* const* d_in, const int* in_sizes, int n_in,
                              void* d_out, int out_size, void* d_ws,
                              size_t ws_size, hipStream_t stream) {
  const float* x    = (const float*)d_in[0];
  const float* W1   = (const float*)d_in[1];
  const float* b1   = (const float*)d_in[2];
  const float* Wc   = (const float*)d_in[3];
  const float* bc   = (const float*)d_in[4];
  const float* cutb = (const float*)d_in[5];
  const float* bmat = (const float*)d_in[6];
  const float* hmat = (const float*)d_in[7];
  const float* amat = (const float*)d_in[8];
  const float* noise= (const float*)d_in[9];
  const float* W3   = (const float*)d_in[10];
  const float* b3   = (const float*)d_in[11];
  const float* W4   = (const float*)d_in[12];
  const float* b4   = (const float*)d_in[13];
  const float* Wo   = (const float*)d_in[14];
  const float* bo   = (const float*)d_in[15];
  const float* ind  = (const float*)d_in[16];

  float* ws = (float*)d_ws;
  float* S1part = ws;                // 1,024,000 floats
  float* spsum  = ws + 1024000;      // 512
  float* spsq   = ws + 1024512;      // 512
  float* wcsum  = ws + 1025024;      // 256
  float* coef   = ws + 1025280;      // 256
  float* konst  = ws + 1025536;      // 32

  kpre_wcsum<<<256, 256, 0, stream>>>(Wc, wcsum);
  k1_gemm<<<dim3(16, 4, 8), 256, 0, stream>>>(x, W1, b1, Wc, S1part, spsum, spsq);
  k2_prep<<<1, 256, 0, stream>>>(spsum, spsq, wcsum, bc, bmat, hmat, amat,
                                 noise, ind, coef, konst);
  k3_tail<<<125, 256, 0, stream>>>(S1part, coef, konst, cutb, W3, b3, W4, b4,
                                   Wo, bo, (float*)d_out);
}

// Round 2
// 59.163 us; speedup vs baseline: 2.6036x; 2.6036x over previous
//
#include <hip/hip_runtime.h>
#include <math.h>

#define B_ 1000
#define D_ 8
#define PRE_ 98
#define NXT_ 2048
#define J_ 32
#define K_ 64
#define A_ 5

typedef __attribute__((ext_vector_type(8))) __bf16 bf16x8;
typedef __attribute__((ext_vector_type(4))) float f32x4;
typedef __attribute__((ext_vector_type(8))) unsigned short ushort8;

__device__ __forceinline__ unsigned short f2bf(float f) {
  union { float f; unsigned u; } v;
  v.f = f;
  unsigned r = v.u + 0x7fffu + ((v.u >> 16) & 1u);
  return (unsigned short)(r >> 16);
}

__device__ __forceinline__ void gload16(const void* g, void* l) {
  __builtin_amdgcn_global_load_lds(
      (const __attribute__((address_space(1))) void*)g,
      (__attribute__((address_space(3))) void*)l, 16, 0, 0);
}

// ws layout (float offsets):
//   [0, 1048576)          S1part[oc(4)][1024][8][32]  f32
//   [1048576, +524288)    xsw  [8][1024][128] bf16 (swizzled, k=98 -> 1.0)
//   [1572864, +1048576)   w1sw [8][2048][128] bf16 (swizzled, k=98 -> b1)
//   [2621440, +262144)    wcsw [8][32 ot][32 j][64] bf16 (swizzled)
//   [2883584, 512)        spsum
//   [2884096, 512)        spsq
//   [2884608, 256)        wcsum
//   [2884864, 256)        coef
//   [2885120, 32)         konst

__global__ __launch_bounds__(256) void kcvt(
    const float* __restrict__ x, const float* __restrict__ W1,
    const float* __restrict__ b1, const float* __restrict__ Wc,
    unsigned short* __restrict__ xsw, unsigned short* __restrict__ w1sw,
    unsigned short* __restrict__ wcsw, float* __restrict__ wcsum) {
  const int bid = blockIdx.x, tid = threadIdx.x;
  if (bid < 1024) {                       // W1 + bias fold, swizzled
    int chunk = bid * 256 + tid;          // [0, 262144)
    int gr = chunk >> 4;                  // global row [0,16384)
    int t = chunk & 15;
    int d = gr >> 11, orow = gr & 2047;
    int th = t ^ (orow & 7);
    int k0 = th * 8;
    const float* src = W1 + (size_t)(d * 2048 + orow) * 98;
    float bias = b1[d * 2048 + orow];
    ushort8 v;
#pragma unroll
    for (int e = 0; e < 8; ++e) {
      int k = k0 + e;
      float f = (k < 98) ? src[k] : ((k == 98) ? bias : 0.0f);
      v[e] = f2bf(f);
    }
    *(ushort8*)(w1sw + (size_t)chunk * 8) = v;
  } else if (bid < 1536) {                // x + ones column, swizzled
    int chunk = (bid - 1024) * 256 + tid; // [0, 131072)
    int gr = chunk >> 4;                  // [0, 8192)
    int t = chunk & 15;
    int d = gr >> 10, r = gr & 1023;
    int th = t ^ (r & 7);
    int k0 = th * 8;
    ushort8 v;
    if (r < B_) {
      const float* src = x + (size_t)r * (D_ * PRE_) + d * 98;
#pragma unroll
      for (int e = 0; e < 8; ++e) {
        int k = k0 + e;
        float f = (k < 98) ? src[k] : ((k == 98) ? 1.0f : 0.0f);
        v[e] = f2bf(f);
      }
    } else {
#pragma unroll
      for (int e = 0; e < 8; ++e) v[e] = 0;
    }
    *(ushort8*)(xsw + (size_t)chunk * 8) = v;
  } else if (bid < 1792) {                // Wc tiles, swizzled
    int chunk = (bid - 1536) * 256 + tid; // [0, 65536)
    int rw = chunk >> 3;                  // [0, 8192)
    int t = chunk & 7;
    int d = rw >> 10, rem = rw & 1023;
    int ot = rem >> 5, j = rem & 31;
    int th = t ^ (j & 7);
    int o0 = ot * 64 + th * 8;
    const float* src = Wc + (size_t)(d * J_ + j) * NXT_ + o0;
    ushort8 v;
#pragma unroll
    for (int e = 0; e < 8; ++e) v[e] = f2bf(src[e]);
    *(ushort8*)(wcsw + (size_t)chunk * 8) = v;
  } else {                                // wcsum rows
    __shared__ float red[256];
    int dj = bid - 1792;
    const float* p = Wc + (size_t)dj * NXT_;
    float s = 0.0f;
    for (int i = tid; i < NXT_; i += 256) s += p[i];
    red[tid] = s;
    __syncthreads();
    for (int st = 128; st; st >>= 1) {
      if (tid < st) red[tid] += red[tid + st];
      __syncthreads();
    }
    if (tid == 0) wcsum[dj] = red[0];
  }
}

__global__ __launch_bounds__(256) void k1_mfma(
    const unsigned short* __restrict__ xsw,
    const unsigned short* __restrict__ w1sw,
    const unsigned short* __restrict__ wcsw, float* __restrict__ S1part,
    float* __restrict__ spsum, float* __restrict__ spsq) {
  __shared__ __align__(16) char smem[49152];
  unsigned short* x_l = (unsigned short*)smem;            // [64][128] swz
  unsigned short* w_l = (unsigned short*)(smem + 16384);  // [64][128] swz
  unsigned short* wc_l = (unsigned short*)(smem + 32768); // [2][32][64] swz
  unsigned short* p_l = (unsigned short*)(smem + 40960);  // [64][64] swz
  float* red = (float*)smem;

  const int bt = blockIdx.x, oc = blockIdx.y, d = blockIdx.z;
  const int tid = threadIdx.x;
  const int wave = tid >> 6, lane = tid & 63;
  const int lr = lane & 15, kg = lane >> 4;
  const int row0 = wave * 16;
  const int rA = row0 + lr;
  const int keyA = (rA & 7) << 4;

  const unsigned short* xg = xsw + (size_t)(d * 1024 + bt * 64) * 128;
  const unsigned short* w1g0 = w1sw + (size_t)(d * 2048 + oc * 512) * 128;
  const unsigned short* wcg0 = wcsw + (size_t)(d * 32 + oc * 8) * 2048;

  for (int c = wave; c < 16; c += 4)
    gload16(xg + c * 512 + lane * 8, smem + c * 1024);
  for (int c = wave; c < 16; c += 4)
    gload16(w1g0 + c * 512 + lane * 8, smem + 16384 + c * 1024);
  gload16(wcg0 + wave * 512 + lane * 8, smem + 32768 + wave * 1024);

  f32x4 acc2[2] = {};
  float lsum = 0.0f, lsq = 0.0f;

  for (int ot = 0; ot < 8; ++ot) {
    __syncthreads();  // staged tiles landed (vmcnt drained); prev p_l reads done
    f32x4 acc[4] = {};
#pragma unroll
    for (int ks = 0; ks < 4; ++ks) {
      bf16x8 a = *(const bf16x8*)((const char*)x_l + rA * 256 +
                                  ((ks * 64 + kg * 16) ^ keyA));
#pragma unroll
      for (int n = 0; n < 4; ++n) {
        int rB = n * 16 + lr;
        bf16x8 b = *(const bf16x8*)((const char*)w_l + rB * 256 +
                                    ((ks * 64 + kg * 16) ^ ((rB & 7) << 4)));
        acc[n] = __builtin_amdgcn_mfma_f32_16x16x32_bf16(a, b, acc[n], 0, 0, 0);
      }
    }
    // epilogue: relu + stats + bf16 + swizzled P write
#pragma unroll
    for (int n = 0; n < 4; ++n) {
#pragma unroll
      for (int j = 0; j < 4; ++j) {
        float v = fmaxf(acc[n][j], 0.0f);
        lsum += v;
        lsq = fmaf(v, v, lsq);
        int pr = row0 + kg * 4 + j;
        int pc = (n * 16 + lr) * 2;
        *(unsigned short*)((char*)p_l + pr * 128 + (pc ^ ((pr & 7) << 4))) =
            f2bf(v);
      }
    }
    __syncthreads();  // p_l ready; w_l/wc_l[cur^1] safe to overwrite
    if (ot < 7) {
      const unsigned short* w1g = w1g0 + (size_t)(ot + 1) * 8192;
      for (int c = wave; c < 16; c += 4)
        gload16(w1g + c * 512 + lane * 8, smem + 16384 + c * 1024);
      const unsigned short* wcg = wcg0 + (size_t)(ot + 1) * 2048;
      gload16(wcg + wave * 512 + lane * 8,
              smem + 32768 + ((ot + 1) & 1) * 4096 + wave * 1024);
    }
    const char* wcb = (const char*)wc_l + (ot & 1) * 4096;
#pragma unroll
    for (int ks = 0; ks < 2; ++ks) {
      bf16x8 a = *(const bf16x8*)((const char*)p_l + rA * 128 +
                                  ((ks * 64 + kg * 16) ^ keyA));
#pragma unroll
      for (int n = 0; n < 2; ++n) {
        int rB = n * 16 + lr;
        bf16x8 b = *(const bf16x8*)(wcb + rB * 128 +
                                    ((ks * 64 + kg * 16) ^ ((rB & 7) << 4)));
        acc2[n] = __builtin_amdgcn_mfma_f32_16x16x32_bf16(a, b, acc2[n], 0, 0, 0);
      }
    }
  }

  // S1 partial write: rows 1000..1023 are exact zeros (padded inputs), kept
#pragma unroll
  for (int n = 0; n < 2; ++n) {
#pragma unroll
    for (int j = 0; j < 4; ++j) {
      int row = row0 + kg * 4 + j;
      int gb = bt * 64 + row;
      int col = n * 16 + lr;
      S1part[(((size_t)oc * 1024 + gb) * 8 + d) * 32 + col] = acc2[n][j];
    }
  }
  __syncthreads();
  red[tid] = lsum;
  red[256 + tid] = lsq;
  __syncthreads();
  for (int st = 128; st; st >>= 1) {
    if (tid < st) {
      red[tid] += red[tid + st];
      red[256 + tid] += red[256 + tid + st];
    }
    __syncthreads();
  }
  if (tid == 0) {
    int bid = (d * 4 + oc) * 16 + bt;
    spsum[bid] = red[0];
    spsq[bid] = red[256];
  }
}

__global__ __launch_bounds__(256) void k2_prep(
    const float* __restrict__ spsum, const float* __restrict__ spsq,
    const float* __restrict__ wcsum, const float* __restrict__ bc,
    const float* __restrict__ b_mat, const float* __restrict__ h_mat,
    const float* __restrict__ a_mat, const float* __restrict__ noise,
    const float* __restrict__ indicator, float* __restrict__ coef,
    float* __restrict__ konst) {
  const int tid = threadIdx.x;
  __shared__ float mvals[8], vvals[8];
  __shared__ float sh_gm, sh_inv;
  __shared__ float offs[D_][J_];

  if (tid < 8) {
    float s = 0.0f, q = 0.0f;
    for (int i = 0; i < 64; ++i) {
      s += spsum[tid * 64 + i];
      q += spsq[tid * 64 + i];
    }
    const float inv_cnt = 1.0f / ((float)B_ * (float)NXT_);
    float m = s * inv_cnt;
    mvals[tid] = m;
    vvals[tid] = q * inv_cnt - m * m;
  }
  __syncthreads();
  if (tid == 0) {
    float gm = 0.0f, gv = 0.0f;
    for (int dd = 0; dd < 8; ++dd) {
      gm += mvals[dd];
      gv += vvals[dd];
    }
    gm *= 0.125f;
    gv *= 0.125f;
    sh_gm = gm;
    sh_inv = 1.0f / sqrtf(gv + 1e-6f);
  }
  __syncthreads();
  {
    int dd = tid >> 5, j = tid & 31;
    float hs[A_] = {0, 0, 0, 0, 0};
    for (int k = 0; k < K_; ++k) {
      float indv = indicator[j * K_ + k];
      if (indv != 0.0f) {
        const float* hp = h_mat + ((size_t)dd * K_ + k) * A_;
#pragma unroll
        for (int a = 0; a < A_; ++a) hs[a] = fmaf(indv, hp[a], hs[a]);
      }
    }
    float hv = 0.0f;
#pragma unroll
    for (int a = 0; a < A_; ++a) hv = fmaf(hs[a], a_mat[j * A_ + a], hv);
    float c = b_mat[dd * J_ + j] * hv;
    coef[dd * J_ + j] = c * sh_inv;
    offs[dd][j] = c * (bc[dd * J_ + j] - sh_gm * wcsum[dd * J_ + j] * sh_inv);
  }
  __syncthreads();
  if (tid < J_) {
    float nz = 0.0f;
#pragma unroll
    for (int a = 0; a < A_; ++a)
      nz = fmaf(a_mat[tid * A_ + a], noise[tid * A_ + a], nz);
    float s = nz;
#pragma unroll
    for (int dd = 0; dd < D_; ++dd) s += offs[dd][tid];
    konst[tid] = s;
  }
}

#define W3S 33
#define W4S 99

__global__ __launch_bounds__(256) void k3_tail(
    const float* __restrict__ S1part, const float* __restrict__ coef,
    const float* __restrict__ konst, const float* __restrict__ cutb,
    const float* __restrict__ W3, const float* __restrict__ b3,
    const float* __restrict__ W4, const float* __restrict__ b4,
    const float* __restrict__ Wo, const float* __restrict__ bo,
    float* __restrict__ out) {
  __shared__ float W3l[98 * W3S];
  __shared__ float W4l[49 * W4S];
  __shared__ float Wol[10 * 49];
  __shared__ float b3l[98], b4l[49], bol[10];
  __shared__ float cutl[32], coefl[256], konstl[32];
  __shared__ float h1[8][32];
  __shared__ float h2[8][100];
  __shared__ float h3[8][52];
  __shared__ float lg[8][10];
  __shared__ float lsel[8];

  const int tid = threadIdx.x;
  for (int idx = tid; idx < 98 * 32; idx += 256) {
    int o = idx >> 5, j = idx & 31;
    W3l[o * W3S + j] = W3[idx];
  }
  for (int idx = tid; idx < 49 * 98; idx += 256) {
    int o = idx / 98, k = idx - o * 98;
    W4l[o * W4S + k] = W4[idx];
  }
  for (int idx = tid; idx < 490; idx += 256) Wol[idx] = Wo[idx];
  if (tid < 98) b3l[tid] = b3[tid];
  if (tid < 49) b4l[tid] = b4[tid];
  if (tid < 10) bol[tid] = bo[tid];
  if (tid < 32) {
    cutl[tid] = cutb[tid];
    konstl[tid] = konst[tid];
  }
  coefl[tid] = coef[tid];
  __syncthreads();

  const int row = tid >> 5, lane = tid & 31;
  const int b = blockIdx.x * 8 + row;  // 125*8 = 1000 exactly

  float rsum = konstl[lane];
#pragma unroll
  for (int dd = 0; dd < D_; ++dd) {
    float s = 0.0f;
#pragma unroll
    for (int ocx = 0; ocx < 4; ++ocx)
      s += S1part[(((size_t)ocx * 1024 + b) * 8 + dd) * 32 + lane];
    rsum = fmaf(coefl[dd * J_ + lane], s, rsum);
  }
  h1[row][lane] = fmaxf(rsum + cutl[lane], 0.0f);
  __syncthreads();

  for (int o = lane; o < 98; o += 32) {
    float a = b3l[o];
#pragma unroll
    for (int j = 0; j < 32; ++j) a = fmaf(h1[row][j], W3l[o * W3S + j], a);
    h2[row][o] = fmaxf(a, 0.0f);
  }
  __syncthreads();

  for (int o = lane; o < 49; o += 32) {
    float a = b4l[o];
    for (int k = 0; k < 98; ++k) a = fmaf(h2[row][k], W4l[o * W4S + k], a);
    h3[row][o] = fmaxf(a, 0.0f);
  }
  __syncthreads();

  if (lane < 10) {
    float a = bol[lane];
#pragma unroll
    for (int k = 0; k < 49; ++k) a = fmaf(h3[row][k], Wol[lane * 49 + k], a);
    lg[row][lane] = a;
  }
  __syncthreads();
  if (lane == 0) {
    float mx = lg[row][0];
    for (int i = 1; i < 10; ++i) mx = fmaxf(mx, lg[row][i]);
    float se = 0.0f;
    for (int i = 0; i < 10; ++i) se += expf(lg[row][i] - mx);
    lsel[row] = mx + logf(se);
  }
  __syncthreads();
  if (lane < 10) out[(size_t)b * 10 + lane] = lg[row][lane] - lsel[row];
}

extern "C" void kernel_launch(void* const* d_in, const int* in_sizes, int n_in,
                              void* d_out, int out_size, void* d_ws,
                              size_t ws_size, hipStream_t stream) {
  const float* x = (const float*)d_in[0];
  const float* W1 = (const float*)d_in[1];
  const float* b1 = (const float*)d_in[2];
  const float* Wc = (const float*)d_in[3];
  const float* bc = (const float*)d_in[4];
  const float* cutb = (const float*)d_in[5];
  const float* bmat = (const float*)d_in[6];
  const float* hmat = (const float*)d_in[7];
  const float* amat = (const float*)d_in[8];
  const float* noise = (const float*)d_in[9];
  const float* W3 = (const float*)d_in[10];
  const float* b3 = (const float*)d_in[11];
  const float* W4 = (const float*)d_in[12];
  const float* b4 = (const float*)d_in[13];
  const float* Wo = (const float*)d_in[14];
  const float* bo = (const float*)d_in[15];
  const float* ind = (const float*)d_in[16];

  float* ws = (float*)d_ws;
  float* S1part = ws;                                  // 1,048,576 f
  unsigned short* xsw = (unsigned short*)(ws + 1048576);   // 1,048,576 us
  unsigned short* w1sw = (unsigned short*)(ws + 1572864);  // 2,097,152 us
  unsigned short* wcsw = (unsigned short*)(ws + 2621440);  // 524,288 us
  float* spsum = ws + 2883584;
  float* spsq = ws + 2884096;
  float* wcsum = ws + 2884608;
  float* coef = ws + 2884864;
  float* konst = ws + 2885120;

  kcvt<<<2048, 256, 0, stream>>>(x, W1, b1, Wc, xsw, w1sw, wcsw, wcsum);
  k1_mfma<<<dim3(16, 4, 8), 256, 0, stream>>>(xsw, w1sw, wcsw, S1part, spsum,
                                              spsq);
  k2_prep<<<1, 256, 0, stream>>>(spsum, spsq, wcsum, bc, bmat, hmat, amat,
                                 noise, ind, coef, konst);
  k3_tail<<<125, 256, 0, stream>>>(S1part, coef, konst, cutb, W3, b3, W4, b4,
                                   Wo, bo, (float*)d_out);
}

// Round 3
// 51.967 us; speedup vs baseline: 2.9641x; 1.1385x over previous
//
#include <hip/hip_runtime.h>
#include <math.h>

#define B_ 1000
#define D_ 8
#define PRE_ 98
#define NXT_ 2048
#define J_ 32
#define K_ 64
#define A_ 5

typedef __attribute__((ext_vector_type(8))) __bf16 bf16x8;
typedef __attribute__((ext_vector_type(4))) float f32x4;
typedef __attribute__((ext_vector_type(16))) float f32x16;
typedef __attribute__((ext_vector_type(8))) unsigned short us8;

__device__ __forceinline__ unsigned short f2bf(float f) {
  union { float f; unsigned u; } v;
  v.f = f;
  unsigned r = v.u + 0x7fffu + ((v.u >> 16) & 1u);
  return (unsigned short)(r >> 16);
}

__device__ __forceinline__ unsigned cvtpk(float lo, float hi) {
  unsigned r;
  asm("v_cvt_pk_bf16_f32 %0, %1, %2" : "=v"(r) : "v"(lo), "v"(hi));
  return r;
}

__device__ __forceinline__ void gload16(const void* g, void* l) {
  __builtin_amdgcn_global_load_lds(
      (const __attribute__((address_space(1))) void*)g,
      (__attribute__((address_space(3))) void*)l, 16, 0, 0);
}

// ws layout (float offsets):
//   [0, 1048576)          S1part[oc(4)][1024][8][32]  f32
//   [1048576, 1572864)    xsw  [8][1024 rows][256B swizzled] bf16 (k=98 -> 1.0)
//   [1572864, 2621440)    w1sw [8][2048 rows][256B swizzled] bf16 (k=98 -> b1)
//   [2621440, 2883584)    wcarr[1024 frags][64 lanes][8] bf16 (fragment-linear)
//   [2883584, 2885632)    spsum[2048]  (per-wave partials)
//   [2885632, 2887680)    spsq [2048]
//   [2887680, 2887936)    wcsum[256]

__global__ __launch_bounds__(256) void kcvt(
    const float* __restrict__ x, const float* __restrict__ W1,
    const float* __restrict__ b1, const float* __restrict__ Wc,
    unsigned short* __restrict__ xsw, unsigned short* __restrict__ w1sw,
    unsigned short* __restrict__ wcarr, float* __restrict__ wcsum) {
  const int bid = blockIdx.x, tid = threadIdx.x;
  if (bid < 1024) {                        // W1 + bias fold, swizzled rows
    int chunk = bid * 256 + tid;           // [0, 262144)
    int gr = chunk >> 4;                   // row [0,16384)
    int t = chunk & 15;
    int d = gr >> 11, orow = gr & 2047;
    int th = t ^ (orow & 7);
    int k0 = th * 8;
    const float* src = W1 + (size_t)(d * 2048 + orow) * 98;
    float bias = b1[d * 2048 + orow];
    us8 v;
#pragma unroll
    for (int e = 0; e < 8; ++e) {
      int k = k0 + e;
      float f = (k < 98) ? src[k] : ((k == 98) ? bias : 0.0f);
      v[e] = f2bf(f);
    }
    *(us8*)(w1sw + (size_t)chunk * 8) = v;
  } else if (bid < 1536) {                 // x + ones column, swizzled rows
    int chunk = (bid - 1024) * 256 + tid;  // [0, 131072)
    int gr = chunk >> 4;                   // [0, 8192)
    int t = chunk & 15;
    int d = gr >> 10, r = gr & 1023;
    int th = t ^ (r & 7);
    int k0 = th * 8;
    us8 v;
    if (r < B_) {
      const float* src = x + (size_t)r * (D_ * PRE_) + d * 98;
#pragma unroll
      for (int e = 0; e < 8; ++e) {
        int k = k0 + e;
        float f = (k < 98) ? src[k] : ((k == 98) ? 1.0f : 0.0f);
        v[e] = f2bf(f);
      }
    } else {
#pragma unroll
      for (int e = 0; e < 8; ++e) v[e] = 0;
    }
    *(us8*)(xsw + (size_t)chunk * 8) = v;
  } else if (bid < 1792) {                 // Wc fragment-linear
    int chunk = (bid - 1536) * 256 + tid;  // [0, 65536)
    int fid = chunk >> 6;                  // [0, 1024)
    int l = chunk & 63;
    int t = fid & 3, ot = (fid >> 2) & 7, oc = (fid >> 5) & 3, d = fid >> 7;
    int j = l & 31;
    int o = oc * 512 + ot * 64 + t * 16 + (l >> 5) * 8;
    const float* src = Wc + (size_t)(d * J_ + j) * NXT_ + o;
    us8 v;
#pragma unroll
    for (int e = 0; e < 8; ++e) v[e] = f2bf(src[e]);
    *(us8*)(wcarr + (size_t)chunk * 8) = v;
  } else {                                 // wcsum rows
    __shared__ float red[256];
    int dj = bid - 1792;
    const float* p = Wc + (size_t)dj * NXT_;
    float s = 0.0f;
    for (int i = tid; i < NXT_; i += 256) s += p[i];
    red[tid] = s;
    __syncthreads();
    for (int st = 128; st; st >>= 1) {
      if (tid < st) red[tid] += red[tid + st];
      __syncthreads();
    }
    if (tid == 0) wcsum[dj] = red[0];
  }
}

__global__ __launch_bounds__(256) void k1_mfma(
    const unsigned short* __restrict__ xsw,
    const unsigned short* __restrict__ w1sw,
    const unsigned short* __restrict__ wcarr, float* __restrict__ S1part,
    float* __restrict__ spsum, float* __restrict__ spsq) {
  __shared__ __align__(16) char smem[49152];  // w1 dbuf 2x16K @0, x 16K @32768

  const int id = blockIdx.x;
  const int d = id & 7;            // XCD-pinned: all of device d on one XCD
  const int bt = (id >> 3) & 15;
  const int oc = (id >> 7) & 3;
  const int tid = threadIdx.x;
  const int wave = tid >> 6, lane = tid & 63;
  const int oh = wave >> 1, bh = wave & 1;
  const int l31 = lane & 31, hi = lane >> 5;
  const bool lo_half = (hi == 0);

  const unsigned short* xg = xsw + (size_t)(d * 1024 + bt * 64) * 128;
  const unsigned short* w1g = w1sw + (size_t)(d * 2048 + oc * 512) * 128;
  const unsigned short* wcg = wcarr + (size_t)((d * 4 + oc) * 8) * 2048;

  // prologue: stage x tile + W1 tile 0
#pragma unroll
  for (int i = 0; i < 4; ++i) {
    int c = wave * 4 + i;
    gload16(xg + c * 512 + lane * 8, smem + 32768 + c * 1024);
    gload16(w1g + c * 512 + lane * 8, smem + c * 1024);
  }
  __syncthreads();

  // x fragments -> registers (reused across all 8 o-tiles)
  const int rb = bh * 32 + l31;
  const int keyB = (rb & 7) << 4;
  bf16x8 xf[8];
#pragma unroll
  for (int ks = 0; ks < 8; ++ks)
    xf[ks] = *(const bf16x8*)(smem + 32768 + rb * 256 +
                              ((ks * 32 + hi * 16) ^ keyB));

  const int ra = oh * 32 + l31;
  const int keyA = (ra & 7) << 4;

  f32x16 acc2 = {};
  float lsum = 0.0f, lsq = 0.0f;

#pragma unroll
  for (int ot = 0; ot < 8; ++ot) {
    const char* wbuf = smem + (ot & 1) * 16384;
    if (ot < 7) {  // early-issue next W1 tile into other buffer
      const unsigned short* src = w1g + (size_t)(ot + 1) * 8192;
      char* dst = smem + ((ot + 1) & 1) * 16384;
#pragma unroll
      for (int i = 0; i < 4; ++i) {
        int c = wave * 4 + i;
        gload16(src + c * 512 + lane * 8, dst + c * 1024);
      }
    }
    bf16x8 wc0 = *(const bf16x8*)(wcg + ((size_t)ot * 4 + oh * 2 + 0) * 512 +
                                  lane * 8);
    bf16x8 wc1 = *(const bf16x8*)(wcg + ((size_t)ot * 4 + oh * 2 + 1) * 512 +
                                  lane * 8);

    // GEMM1: C[o][b] for this wave's (oh, bh) 32x32 quadrant, K=128
    f32x16 acc = {};
#pragma unroll
    for (int ks = 0; ks < 8; ++ks) {
      bf16x8 a = *(const bf16x8*)(wbuf + ra * 256 +
                                  ((ks * 32 + hi * 16) ^ keyA));
      acc = __builtin_amdgcn_mfma_f32_32x32x16_bf16(a, xf[ks], acc, 0, 0, 0);
    }

    // epilogue: relu + stats, then in-register P fragments (no LDS)
    float v[16];
#pragma unroll
    for (int r = 0; r < 16; ++r) {
      v[r] = fmaxf(acc[r], 0.0f);
      lsum += v[r];
      lsq = fmaf(v[r], v[r], lsq);
    }
#pragma unroll
    for (int t = 0; t < 2; ++t) {
      unsigned A0 = cvtpk(v[8 * t + 0], v[8 * t + 1]);
      unsigned A1 = cvtpk(v[8 * t + 2], v[8 * t + 3]);
      unsigned B0 = cvtpk(v[8 * t + 4], v[8 * t + 5]);
      unsigned B1 = cvtpk(v[8 * t + 6], v[8 * t + 7]);
      unsigned sA0 = __shfl_xor(A0, 32);
      unsigned sA1 = __shfl_xor(A1, 32);
      unsigned sB0 = __shfl_xor(B0, 32);
      unsigned sB1 = __shfl_xor(B1, 32);
      union { unsigned u[4]; bf16x8 v; } f;
      f.u[0] = lo_half ? A0 : sB0;
      f.u[1] = lo_half ? A1 : sB1;
      f.u[2] = lo_half ? sA0 : B0;
      f.u[3] = lo_half ? sA1 : B1;
      acc2 = __builtin_amdgcn_mfma_f32_32x32x16_bf16(t == 0 ? wc0 : wc1, f.v,
                                                     acc2, 0, 0, 0);
    }
    __syncthreads();  // drains next-tile stage; gates buffer reuse
  }

  // cross-wave reduction over oh pairs (x region is dead -> scratch)
  if (oh == 1) {
    char* rbase = smem + 32768 + bh * 5120 + lane * 80;
#pragma unroll
    for (int g = 0; g < 4; ++g) {
      f32x4 q = {acc2[4 * g + 0], acc2[4 * g + 1], acc2[4 * g + 2],
                 acc2[4 * g + 3]};
      *(f32x4*)(rbase + g * 16) = q;
    }
  }
  __syncthreads();
  if (oh == 0) {
    const char* rbase = smem + 32768 + bh * 5120 + lane * 80;
    const int b = bt * 64 + bh * 32 + l31;
    float* s1b = S1part + (((size_t)oc * 1024 + b) * 8 + d) * 32;
#pragma unroll
    for (int g = 0; g < 4; ++g) {
      f32x4 p = *(const f32x4*)(rbase + g * 16);
      f32x4 q = {acc2[4 * g + 0] + p[0], acc2[4 * g + 1] + p[1],
                 acc2[4 * g + 2] + p[2], acc2[4 * g + 3] + p[3]};
      int j0 = 8 * g + 4 * hi;
      *(f32x4*)(s1b + j0) = q;
    }
  }

  // stats: per-wave shuffle reduction, one slot per wave
#pragma unroll
  for (int off = 32; off; off >>= 1) {
    lsum += __shfl_down(lsum, off);
    lsq += __shfl_down(lsq, off);
  }
  if (lane == 0) {
    int sbid = ((d * 4 + oc) * 16 + bt) * 4 + wave;
    spsum[sbid] = lsum;
    spsq[sbid] = lsq;
  }
}

#define W3S 33
#define W4S 99

__global__ __launch_bounds__(256) void k3_tail(
    const float* __restrict__ S1part, const float* __restrict__ spsum,
    const float* __restrict__ spsq, const float* __restrict__ wcsum,
    const float* __restrict__ bc, const float* __restrict__ b_mat,
    const float* __restrict__ h_mat, const float* __restrict__ a_mat,
    const float* __restrict__ noise, const float* __restrict__ indicator,
    const float* __restrict__ cutb, const float* __restrict__ W3,
    const float* __restrict__ b3, const float* __restrict__ W4,
    const float* __restrict__ b4, const float* __restrict__ Wo,
    const float* __restrict__ bo, float* __restrict__ out) {
  __shared__ float W3l[98 * W3S];
  __shared__ float W4l[49 * W4S];
  __shared__ float Wol[10 * 49];
  __shared__ float b3l[98], b4l[49], bol[10];
  __shared__ float cutl[32], coefl[256], konstl[32];
  __shared__ float mvals[8], vvals[8];
  __shared__ float sh_gm, sh_inv;
  __shared__ float offs[D_][J_];
  __shared__ float h1[8][32];
  __shared__ float h2[8][100];
  __shared__ float h3[8][52];
  __shared__ float lg[8][10];
  __shared__ float lsel[8];

  const int tid = threadIdx.x;

  // ---- weight preloads ----
  for (int idx = tid; idx < 98 * 32; idx += 256) {
    int o = idx >> 5, j = idx & 31;
    W3l[o * W3S + j] = W3[idx];
  }
  for (int idx = tid; idx < 49 * 98; idx += 256) {
    int o = idx / 98, k = idx - o * 98;
    W4l[o * W4S + k] = W4[idx];
  }
  for (int idx = tid; idx < 490; idx += 256) Wol[idx] = Wo[idx];
  if (tid < 98) b3l[tid] = b3[tid];
  if (tid < 49) b4l[tid] = b4[tid];
  if (tid < 10) bol[tid] = bo[tid];
  if (tid < 32) cutl[tid] = cutb[tid];

  // ---- fused prep (was k2): stats -> coef/konst ----
  if (tid < 8) {
    float s = 0.0f, q = 0.0f;
    for (int i = 0; i < 256; ++i) {
      s += spsum[tid * 256 + i];
      q += spsq[tid * 256 + i];
    }
    const float inv_cnt = 1.0f / ((float)B_ * (float)NXT_);
    float m = s * inv_cnt;
    mvals[tid] = m;
    vvals[tid] = q * inv_cnt - m * m;
  }
  __syncthreads();
  if (tid == 0) {
    float gm = 0.0f, gv = 0.0f;
    for (int dd = 0; dd < 8; ++dd) {
      gm += mvals[dd];
      gv += vvals[dd];
    }
    gm *= 0.125f;
    gv *= 0.125f;
    sh_gm = gm;
    sh_inv = 1.0f / sqrtf(gv + 1e-6f);
  }
  __syncthreads();
  {
    int dd = tid >> 5, j = tid & 31;
    float hs[A_] = {0, 0, 0, 0, 0};
    for (int k = 0; k < K_; ++k) {
      float indv = indicator[j * K_ + k];
      if (indv != 0.0f) {
        const float* hp = h_mat + ((size_t)dd * K_ + k) * A_;
#pragma unroll
        for (int a = 0; a < A_; ++a) hs[a] = fmaf(indv, hp[a], hs[a]);
      }
    }
    float hv = 0.0f;
#pragma unroll
    for (int a = 0; a < A_; ++a) hv = fmaf(hs[a], a_mat[j * A_ + a], hv);
    float c = b_mat[dd * J_ + j] * hv;
    coefl[tid] = c * sh_inv;
    offs[dd][j] = c * (bc[dd * J_ + j] - sh_gm * wcsum[dd * J_ + j] * sh_inv);
  }
  __syncthreads();
  if (tid < J_) {
    float nz = 0.0f;
#pragma unroll
    for (int a = 0; a < A_; ++a)
      nz = fmaf(a_mat[tid * A_ + a], noise[tid * A_ + a], nz);
    float s = nz;
#pragma unroll
    for (int dd = 0; dd < D_; ++dd) s += offs[dd][tid];
    konstl[tid] = s;
  }
  __syncthreads();

  // ---- tail MLP ----
  const int row = tid >> 5, lane = tid & 31;
  const int b = blockIdx.x * 8 + row;  // 125*8 = 1000 exactly

  float rsum = konstl[lane];
#pragma unroll
  for (int dd = 0; dd < D_; ++dd) {
    float s = 0.0f;
#pragma unroll
    for (int ocx = 0; ocx < 4; ++ocx)
      s += S1part[(((size_t)ocx * 1024 + b) * 8 + dd) * 32 + lane];
    rsum = fmaf(coefl[dd * J_ + lane], s, rsum);
  }
  h1[row][lane] = fmaxf(rsum + cutl[lane], 0.0f);
  __syncthreads();

  for (int o = lane; o < 98; o += 32) {
    float a = b3l[o];
#pragma unroll
    for (int j = 0; j < 32; ++j) a = fmaf(h1[row][j], W3l[o * W3S + j], a);
    h2[row][o] = fmaxf(a, 0.0f);
  }
  __syncthreads();

  for (int o = lane; o < 49; o += 32) {
    float a = b4l[o];
    for (int k = 0; k < 98; ++k) a = fmaf(h2[row][k], W4l[o * W4S + k], a);
    h3[row][o] = fmaxf(a, 0.0f);
  }
  __syncthreads();

  if (lane < 10) {
    float a = bol[lane];
#pragma unroll
    for (int k = 0; k < 49; ++k) a = fmaf(h3[row][k], Wol[lane * 49 + k], a);
    lg[row][lane] = a;
  }
  __syncthreads();
  if (lane == 0) {
    float mx = lg[row][0];
    for (int i = 1; i < 10; ++i) mx = fmaxf(mx, lg[row][i]);
    float se = 0.0f;
    for (int i = 0; i < 10; ++i) se += expf(lg[row][i] - mx);
    lsel[row] = mx + logf(se);
  }
  __syncthreads();
  if (lane < 10) out[(size_t)b * 10 + lane] = lg[row][lane] - lsel[row];
}

extern "C" void kernel_launch(void* const* d_in, const int* in_sizes, int n_in,
                              void* d_out, int out_size, void* d_ws,
                              size_t ws_size, hipStream_t stream) {
  const float* x = (const float*)d_in[0];
  const float* W1 = (const float*)d_in[1];
  const float* b1 = (const float*)d_in[2];
  const float* Wc = (const float*)d_in[3];
  const float* bc = (const float*)d_in[4];
  const float* cutb = (const float*)d_in[5];
  const float* bmat = (const float*)d_in[6];
  const float* hmat = (const float*)d_in[7];
  const float* amat = (const float*)d_in[8];
  const float* noise = (const float*)d_in[9];
  const float* W3 = (const float*)d_in[10];
  const float* b3 = (const float*)d_in[11];
  const float* W4 = (const float*)d_in[12];
  const float* b4 = (const float*)d_in[13];
  const float* Wo = (const float*)d_in[14];
  const float* bo = (const float*)d_in[15];
  const float* ind = (const float*)d_in[16];

  float* ws = (float*)d_ws;
  float* S1part = ws;                                       // [0, 1048576)
  unsigned short* xsw = (unsigned short*)(ws + 1048576);    // 1,048,576 us
  unsigned short* w1sw = (unsigned short*)(ws + 1572864);   // 2,097,152 us
  unsigned short* wcarr = (unsigned short*)(ws + 2621440);  // 524,288 us
  float* spsum = ws + 2883584;                              // 2048
  float* spsq = ws + 2885632;                               // 2048
  float* wcsum = ws + 2887680;                              // 256

  kcvt<<<2048, 256, 0, stream>>>(x, W1, b1, Wc, xsw, w1sw, wcarr, wcsum);
  k1_mfma<<<512, 256, 0, stream>>>(xsw, w1sw, wcarr, S1part, spsum, spsq);
  k3_tail<<<125, 256, 0, stream>>>(S1part, spsum, spsq, wcsum, bc, bmat, hmat,
                                   amat, noise, ind, cutb, W3, b3, W4, b4, Wo,
                                   bo, (float*)d_out);
}